// Round 10
// baseline (276.559 us; speedup 1.0000x reference)
//
#include <hip/hip_runtime.h>
#include <math.h>

#define BSZ 32
#define CH  256

typedef short  bf16x8 __attribute__((ext_vector_type(8)));
typedef float  f32x4  __attribute__((ext_vector_type(4)));
typedef unsigned short ushort_t;
typedef unsigned int   uint_t;

#define MFMA(a, b, c) __builtin_amdgcn_mfma_f32_16x16x32_bf16((a), (b), (c), 0, 0, 0)

__device__ __forceinline__ ushort_t f2b(float f) {
    uint_t u = __builtin_bit_cast(uint_t, f);
    uint_t r = (u + 0x7FFFu + ((u >> 16) & 1u)) >> 16;   // RTNE
    return (ushort_t)r;
}
__device__ __forceinline__ float b2f(ushort_t u) {
    uint_t v = ((uint_t)u) << 16;
    return __builtin_bit_cast(float, v);
}
__device__ __forceinline__ uint_t pk2(float a, float b) {
    return (uint_t)f2b(a) | ((uint_t)f2b(b) << 16);
}

// ---------------- kernel 1: per-cell winning edge (last write wins) -------
__global__ void edge_win_kernel(const int* __restrict__ ei, int E, int nb,
                                int* __restrict__ win) {
    int e = blockIdx.x * blockDim.x + threadIdx.x;
    if (e >= E) return;
    int r = ei[e];
    int c = ei[E + e];
    int br = r >> 5, bc = c >> 5;
    if (br == bc && br < nb) {
        atomicMax(&win[br * (BSZ * BSZ) + (r & 31) * BSZ + (c & 31)], e);
    }
}

// ---------------- kernel 1b: winning edges scatter their features ---------
__global__ void edge_feat_kernel(const int* __restrict__ ei,
                                 const float* __restrict__ ev,
                                 const float* __restrict__ pos,
                                 const int* __restrict__ win, int E,
                                 ushort_t* __restrict__ cellinfo) {
    int e = blockIdx.x * blockDim.x + threadIdx.x;
    if (e >= E) return;
    int r = ei[e];
    int c = ei[E + e];
    int br = r >> 5, bc = c >> 5;
    if (br != bc) return;
    int cell = br * 1024 + (r & 31) * 32 + (c & 31);
    if (win[cell] != e) return;
    float d0 = pos[c * 3 + 0] - pos[r * 3 + 0];
    float d1 = pos[c * 3 + 1] - pos[r * 3 + 1];
    float d2 = pos[c * 3 + 2] - pos[r * 3 + 2];
    float d3 = ev[e];
    uint2 w; w.x = pk2(d0, d1); w.y = pk2(d2, d3);
    *(uint2*)&cellinfo[(size_t)cell * 4] = w;
}

// ---------------- kernel 2: weights -> bf16 MFMA-fragment layout ----------
__global__ void wconv_kernel(const float* __restrict__ qkv_w,
                             const float* __restrict__ proj_w,
                             ushort_t* __restrict__ qkv_wf,
                             ushort_t* __restrict__ proj_wf) {
    int i = blockIdx.x * blockDim.x + threadIdx.x;   // (tile,ks,lane)
    int lane = i & 63, ks = (i >> 6) & 7, tile = i >> 9;
    int l15 = lane & 15, lg = lane >> 4;
    if (tile < 48) {
        const float* src = qkv_w + (size_t)(tile * 16 + l15) * 256 + ks * 32 + lg * 8;
        ushort_t* dst = qkv_wf + (size_t)i * 8;
        #pragma unroll
        for (int e = 0; e < 8; ++e) dst[e] = f2b(src[e]);
    }
    if (tile < 16) {
        const float* src = proj_w + (size_t)(tile * 16 + l15) * 256 + ks * 32 + lg * 8;
        ushort_t* dst = proj_wf + (size_t)i * 8;
        #pragma unroll
        for (int e = 0; e < 8; ++e) dst[e] = f2b(src[e]);
    }
}

// ---------------- fused kernel: one leaf / WG, wave = head ----------------
// 256 threads (4 waves). Wave h computes q,k,v for ch [h*64,(h+1)*64) and
// does that head's attention entirely wave-privately: qkv D-fragments are
// converted to scores/PV A/B-fragments through a 1.2 KB wave-private LDS
// scratch (in-order DS => no barriers). Only 2 barriers total:
// B1 (x+cell staged), B3 (xo before proj).
// LDS: xb 16K | xo 16K | cell 8K (swz) | scratch 4x1216
#define LS_XB   0
#define LS_XO   16384
#define LS_CELL 32768
#define LS_SCR  40960
#define LS_TOT  45824

__global__ __launch_bounds__(256, 3)
void fused_attn(const float* __restrict__ x,
                const ushort_t* __restrict__ qkv_wf,
                const float* __restrict__ qkv_b,
                const ushort_t* __restrict__ cellinfo,
                const ushort_t* __restrict__ proj_wf,
                const float* __restrict__ proj_b,
                const float* __restrict__ gate_w,
                const float* __restrict__ gate_b,
                float* __restrict__ out)
{
    __shared__ __align__(16) char smem[LS_TOT];
    ushort_t* xb    = (ushort_t*)(smem + LS_XB);
    ushort_t* xo    = (ushort_t*)(smem + LS_XO);
    ushort_t* cellL = (ushort_t*)(smem + LS_CELL);

    const int t = threadIdx.x;
    const int h = t >> 6, lane = t & 63, l15 = lane & 15, lg = lane >> 4;
    const int bi = blockIdx.x, mbase = bi * 32;
    ushort_t* scr = (ushort_t*)(smem + LS_SCR + h * 1216);

    // ---- P1: stage x -> bf16 LDS (swz8); stage cellinfo (swz16) ---------
    #pragma unroll
    for (int i = 0; i < 8; ++i) {
        int flat = i * 1024 + t * 4;
        int r = flat >> 8, c = flat & 255;
        float4 xv = *(const float4*)&x[(size_t)(mbase + r) * CH + c];
        uint2 wv; wv.x = pk2(xv.x, xv.y); wv.y = pk2(xv.z, xv.w);
        *(uint2*)&xb[r * 256 + (c ^ ((r & 7) << 3))] = wv;
    }
    #pragma unroll
    for (int i = 0; i < 2; ++i) {
        int pid = t * 2 + i;               // 512 pairs of cells (16B each)
        int qi = pid >> 4, p = pid & 15;
        uint4 cv = *(const uint4*)&cellinfo[(size_t)bi * 4096 + qi * 128 + p * 8];
        *(uint4*)&cellL[qi * 128 + ((p ^ (qi & 15)) * 8)] = cv;
    }
    __syncthreads();   // B1

    const int slB = (l15 & 7) << 3;
    const f32x4 zf = {0.f, 0.f, 0.f, 0.f};
    f32x4 acc[4][2];
    bf16x8 xfA[2], xfB[2], wfA[4], wfB[4];

#define LOADX2(dst, kss) { int k0_ = (((kss) * 32) + lg * 8) ^ slB;           \
        dst[0] = *(const bf16x8*)&xb[l15 * 256 + k0_];                        \
        dst[1] = *(const bf16x8*)&xb[(16 + l15) * 256 + k0_]; }

#define LOADW4(dst, tb, kss) { _Pragma("unroll")                              \
        for (int ti_ = 0; ti_ < 4; ++ti_)                                     \
            dst[ti_] = *(const bf16x8*)(qkv_wf                                \
                + ((size_t)(((tb) + ti_) * 8 + (kss))) * 512 + lane * 8); }

#define COMP4(xf, wf, SW) { _Pragma("unroll")                                 \
        for (int ti_ = 0; ti_ < 4; ++ti_) {                                   \
            if (SW) {                                                         \
                acc[ti_][0] = MFMA(wf[ti_], xf[0], acc[ti_][0]);              \
                acc[ti_][1] = MFMA(wf[ti_], xf[1], acc[ti_][1]);              \
            } else {                                                          \
                acc[ti_][0] = MFMA(xf[0], wf[ti_], acc[ti_][0]);              \
                acc[ti_][1] = MFMA(xf[1], wf[ti_], acc[ti_][1]);              \
            } } }

#define GEMM_PHASE(TB, SW) {                                                  \
    _Pragma("unroll")                                                         \
    for (int a_ = 0; a_ < 4; ++a_) { acc[a_][0] = zf; acc[a_][1] = zf; }      \
    LOADX2(xfA, 0); LOADW4(wfA, TB, 0);                                       \
    LOADX2(xfB, 1); LOADW4(wfB, TB, 1);                                       \
    COMP4(xfA, wfA, SW);                                                      \
    LOADX2(xfA, 2); LOADW4(wfA, TB, 2);                                       \
    COMP4(xfB, wfB, SW);                                                      \
    LOADX2(xfB, 3); LOADW4(wfB, TB, 3);                                       \
    COMP4(xfA, wfA, SW);                                                      \
    LOADX2(xfA, 4); LOADW4(wfA, TB, 4);                                       \
    COMP4(xfB, wfB, SW);                                                      \
    LOADX2(xfB, 5); LOADW4(wfB, TB, 5);                                       \
    COMP4(xfA, wfA, SW);                                                      \
    LOADX2(xfA, 6); LOADW4(wfA, TB, 6);                                       \
    COMP4(xfB, wfB, SW);                                                      \
    LOADX2(xfB, 7); LOADW4(wfB, TB, 7);                                       \
    COMP4(xfA, wfA, SW);                                                      \
    COMP4(xfB, wfB, SW); }

    // wave-private 16x32 repack: qkv D-frag (l15=kept, lg*4+j=other) ->
    // MFMA A/B-frag (l15=kept, lg*8+e=other). Row stride 38 (odd word
    // stride 19) => conflict-free b64 writes / b128 reads. DS in-order per
    // wave => no barrier, single buffer.
    auto repack16 = [&](f32x4 a0, f32x4 a1) -> bf16x8 {
        uint2 w0, w1;
        w0.x = pk2(a0[0], a0[1]); w0.y = pk2(a0[2], a0[3]);
        w1.x = pk2(a1[0], a1[1]); w1.y = pk2(a1[2], a1[3]);
        *(uint2*)&scr[l15 * 38 + lg * 4]      = w0;
        *(uint2*)&scr[l15 * 38 + 16 + lg * 4] = w1;
        return *(const bf16x8*)&scr[l15 * 38 + lg * 8];
    };

    // ---- P2: q GEMM (swapped: D[ch][row]) + repack to B-frags -----------
    bf16x8 qld[2][2], kld[2][2], vf[4], cfr[2];
    GEMM_PHASE(h * 4, true);
    #pragma unroll
    for (int ti = 0; ti < 4; ++ti) {
        f32x4 bq = *(const f32x4*)&qkv_b[(h * 4 + ti) * 16 + lg * 4];
        acc[ti][0] += bq; acc[ti][1] += bq;
    }
    #pragma unroll
    for (int qt = 0; qt < 2; ++qt)
        #pragma unroll
        for (int ks2 = 0; ks2 < 2; ++ks2)
            qld[qt][ks2] = repack16(acc[ks2 * 2][qt], acc[ks2 * 2 + 1][qt]);

    // ---- P3: k GEMM + repack to A-frags ---------------------------------
    GEMM_PHASE(16 + h * 4, true);
    #pragma unroll
    for (int ti = 0; ti < 4; ++ti) {
        f32x4 bk = *(const f32x4*)&qkv_b[256 + (h * 4 + ti) * 16 + lg * 4];
        acc[ti][0] += bk; acc[ti][1] += bk;
    }
    #pragma unroll
    for (int kt = 0; kt < 2; ++kt)
        #pragma unroll
        for (int ks2 = 0; ks2 < 2; ++ks2)
            kld[kt][ks2] = repack16(acc[ks2 * 2][kt], acc[ks2 * 2 + 1][kt]);

    // ---- P4: v GEMM (non-swapped: D[row][ch]) + repack to A-frags -------
    GEMM_PHASE(32 + h * 4, false);
    #pragma unroll
    for (int ct = 0; ct < 4; ++ct) {
        float bvs = qkv_b[512 + (h * 4 + ct) * 16 + l15];
        f32x4 bb = {bvs, bvs, bvs, bvs};
        acc[ct][0] += bb; acc[ct][1] += bb;
        vf[ct] = repack16(acc[ct][0], acc[ct][1]);
    }

    // ---- P5: scores MFMA (A=k M=kj, B=q N=qi) -> D[kj][qi] --------------
    f32x4 s[2][2];
    #pragma unroll
    for (int qt = 0; qt < 2; ++qt) { s[qt][0] = zf; s[qt][1] = zf; }
    #pragma unroll
    for (int qt = 0; qt < 2; ++qt)
        #pragma unroll
        for (int ks2 = 0; ks2 < 2; ++ks2)
            #pragma unroll
            for (int kt = 0; kt < 2; ++kt)
                s[qt][kt] = MFMA(kld[kt][ks2], qld[qt][ks2], s[qt][kt]);

    // ---- P6: softmax + gate; kj=32 via mean of raw scores ---------------
    const float gw0 = gate_w[h * 4 + 0], gw1 = gate_w[h * 4 + 1];
    const float gw2 = gate_w[h * 4 + 2], gw3 = gate_w[h * 4 + 3];
    const float gb  = gate_b[h];
    #pragma unroll
    for (int qt = 0; qt < 2; ++qt) {
        int qi = qt * 16 + l15;
        float r[8], gt[8];
        float rawsum = 0.f;
        #pragma unroll
        for (int kt = 0; kt < 2; ++kt) {
            int kj0 = kt * 16 + lg * 4;
            int pb2 = kt * 8 + lg * 2;
            uint4 cA = *(const uint4*)&cellL[qi * 128 + ((pb2 ^ (qi & 15)) * 8)];
            uint4 cB = *(const uint4*)&cellL[qi * 128 + (((pb2 + 1) ^ (qi & 15)) * 8)];
            uint_t d01[4] = {cA.x, cA.z, cB.x, cB.z};
            uint_t d23[4] = {cA.y, cA.w, cB.y, cB.w};
            #pragma unroll
            for (int j = 0; j < 4; ++j) {
                int kj = kj0 + j;
                bool fixed = (kj == qi);
                ushort_t e3b = (ushort_t)(d23[j] >> 16);
                bool valid = (e3b != (ushort_t)0xFFFFu);
                float e3 = b2f(e3b);
                float sb = fixed ? 1.0f : (valid ? e3 : -INFINITY);
                float g;
                if (fixed)      g = gw3 + gb;
                else if (valid) g = b2f((ushort_t)(d01[j] & 0xFFFF)) * gw0
                                  + b2f((ushort_t)(d01[j] >> 16))    * gw1
                                  + b2f((ushort_t)(d23[j] & 0xFFFF)) * gw2
                                  + e3 * gw3 + gb;
                else            g = 0.0f;
                float sraw = s[qt][kt][j];
                rawsum += sraw;
                r[kt * 4 + j]  = sraw * 0.125f + sb;
                gt[kt * 4 + j] = g;
            }
        }
        rawsum += __shfl_xor(rawsum, 16);
        rawsum += __shfl_xor(rawsum, 32);
        float r2 = rawsum * (0.125f / 32.0f) + 1.0f;

        float m = fmaxf(fmaxf(fmaxf(r[0], r[1]), fmaxf(r[2], r[3])),
                        fmaxf(fmaxf(r[4], r[5]), fmaxf(r[6], r[7])));
        m = fmaxf(m, r2);
        m = fmaxf(m, __shfl_xor(m, 16));
        m = fmaxf(m, __shfl_xor(m, 32));
        float sum = 0.f;
        #pragma unroll
        for (int i = 0; i < 8; ++i) { r[i] = __expf(r[i] - m); sum += r[i]; }
        sum += __shfl_xor(sum, 16);
        sum += __shfl_xor(sum, 32);
        float e2 = __expf(r2 - m);
        float inv = 1.0f / (sum + e2);
        float comb32 = e2 * inv + (gw3 + gb);
        float cadd = comb32 * 0.03125f;     // fold kj=32 PV into every entry
        f32x4 ra = {r[0] * inv + gt[0] + cadd, r[1] * inv + gt[1] + cadd,
                    r[2] * inv + gt[2] + cadd, r[3] * inv + gt[3] + cadd};
        f32x4 rb = {r[4] * inv + gt[4] + cadd, r[5] * inv + gt[5] + cadd,
                    r[6] * inv + gt[6] + cadd, r[7] * inv + gt[7] + cadd};
        cfr[qt] = repack16(ra, rb);         // B-frag: l15=qi, lg*8+e = kj
    }

    // ---- P7: PV MFMA (A=v M=ch, B=comb N=qi) -> xo ----------------------
    #pragma unroll
    for (int ct = 0; ct < 4; ++ct) {
        #pragma unroll
        for (int qt = 0; qt < 2; ++qt) {
            f32x4 a2 = zf;
            a2 = MFMA(vf[ct], cfr[qt], a2);
            int qi = qt * 16 + l15;
            uint2 wv;
            wv.x = pk2(a2[0], a2[1]);
            wv.y = pk2(a2[2], a2[3]);
            int c0 = h * 64 + ct * 16 + lg * 4;
            *(uint2*)&xo[qi * 256 + (c0 ^ ((l15 & 7) << 3))] = wv;
        }
    }
    __syncthreads();   // B3: xo read cross-wave by proj

    // ---- P8: proj (wave h: tiles h*4+i), 2-deep weight pipeline ---------
    {
        const int slR = (l15 & 7) << 3;
        bf16x8 pwA[4], pwB[4];
        f32x4 pacc[4][2];
        #pragma unroll
        for (int i = 0; i < 4; ++i) { pacc[i][0] = zf; pacc[i][1] = zf; }

#define LOADPW(dst, kss) { _Pragma("unroll")                                  \
        for (int i_ = 0; i_ < 4; ++i_)                                        \
            dst[i_] = *(const bf16x8*)(proj_wf                                \
                + ((size_t)((h * 4 + i_) * 8 + (kss))) * 512 + lane * 8); }

#define PCOMP(pw, kss) { int k0_ = (kss) * 32 + lg * 8;                       \
        bf16x8 b0_ = *(const bf16x8*)&xo[l15 * 256 + (k0_ ^ slR)];            \
        bf16x8 b1_ = *(const bf16x8*)&xo[(16 + l15) * 256 + (k0_ ^ slR)];     \
        _Pragma("unroll")                                                     \
        for (int i_ = 0; i_ < 4; ++i_) {                                      \
            pacc[i_][0] = MFMA(pw[i_], b0_, pacc[i_][0]);                     \
            pacc[i_][1] = MFMA(pw[i_], b1_, pacc[i_][1]);                     \
        } }

        LOADPW(pwA, 0); LOADPW(pwB, 1);
        PCOMP(pwA, 0);  LOADPW(pwA, 2);
        PCOMP(pwB, 1);  LOADPW(pwB, 3);
        PCOMP(pwA, 2);  LOADPW(pwA, 4);
        PCOMP(pwB, 3);  LOADPW(pwB, 5);
        PCOMP(pwA, 4);  LOADPW(pwA, 6);
        PCOMP(pwB, 5);  LOADPW(pwB, 7);
        PCOMP(pwA, 6);
        PCOMP(pwB, 7);

        #pragma unroll
        for (int i = 0; i < 4; ++i) {
            int n0 = (h * 4 + i) * 16;
            f32x4 bv = *(const f32x4*)&proj_b[n0 + lg * 4];
            f32x4 o0 = pacc[i][0] + bv;
            f32x4 o1 = pacc[i][1] + bv;
            *(f32x4*)&out[(size_t)(mbase + l15) * 256 + n0 + lg * 4]      = o0;
            *(f32x4*)&out[(size_t)(mbase + 16 + l15) * 256 + n0 + lg * 4] = o1;
        }
    }
}

extern "C" void kernel_launch(void* const* d_in, const int* in_sizes, int n_in,
                              void* d_out, int out_size, void* d_ws, size_t ws_size,
                              hipStream_t stream) {
    const float* x      = (const float*)d_in[0];
    const int*   ei     = (const int*)  d_in[1];
    const float* ev     = (const float*)d_in[2];
    const float* pos    = (const float*)d_in[3];
    const float* qkv_w  = (const float*)d_in[4];
    const float* qkv_b  = (const float*)d_in[5];
    const float* proj_w = (const float*)d_in[6];
    const float* proj_b = (const float*)d_in[7];
    const float* gate_w = (const float*)d_in[8];
    const float* gate_b = (const float*)d_in[9];
    float* out = (float*)d_out;

    const int E  = in_sizes[2];
    const int N  = in_sizes[0] / CH;
    const int nb = N / BSZ;

    char* ws = (char*)d_ws;
    int*      win      = (int*)ws;                              // nb*4096 B
    ushort_t* cellinfo = (ushort_t*)(ws + (size_t)nb * 4096);   // nb*8192 B
    size_t off = (size_t)nb * 12288;
    ushort_t* qkv_wf  = (ushort_t*)(ws + off); off += 48 * 8 * 64 * 8 * 2;
    ushort_t* proj_wf = (ushort_t*)(ws + off); off += 16 * 8 * 64 * 8 * 2;

    // one memset covers win (-1) and cellinfo (NaN sentinel) — both 0xFF
    hipMemsetAsync(ws, 0xFF, (size_t)nb * 12288, stream);
    edge_win_kernel<<<(E + 255) / 256, 256, 0, stream>>>(ei, E, nb, win);
    edge_feat_kernel<<<(E + 255) / 256, 256, 0, stream>>>(ei, ev, pos, win, E,
                                                          cellinfo);
    wconv_kernel<<<96, 256, 0, stream>>>(qkv_w, proj_w, qkv_wf, proj_wf);
    fused_attn<<<nb, 256, 0, stream>>>(x, qkv_wf, qkv_b, cellinfo,
                                       proj_wf, proj_b, gate_w, gate_b, out);
}

// Round 11
// 269.601 us; speedup vs baseline: 1.0258x; 1.0258x over previous
//
#include <hip/hip_runtime.h>
#include <math.h>

#define BSZ 32
#define CH  256

typedef short  bf16x8 __attribute__((ext_vector_type(8)));
typedef float  f32x4  __attribute__((ext_vector_type(4)));
typedef unsigned short ushort_t;
typedef unsigned int   uint_t;

#define MFMA(a, b, c) __builtin_amdgcn_mfma_f32_16x16x32_bf16((a), (b), (c), 0, 0, 0)

__device__ __forceinline__ ushort_t f2b(float f) {
    uint_t u = __builtin_bit_cast(uint_t, f);
    uint_t r = (u + 0x7FFFu + ((u >> 16) & 1u)) >> 16;   // RTNE
    return (ushort_t)r;
}
__device__ __forceinline__ float b2f(ushort_t u) {
    uint_t v = ((uint_t)u) << 16;
    return __builtin_bit_cast(float, v);
}
__device__ __forceinline__ uint_t pk2(float a, float b) {
    return (uint_t)f2b(a) | ((uint_t)f2b(b) << 16);
}

// ---------------- kernel 1: per-cell winning edge (last write wins) -------
__global__ void edge_win_kernel(const int* __restrict__ ei, int E, int nb,
                                int* __restrict__ win) {
    int e = blockIdx.x * blockDim.x + threadIdx.x;
    if (e >= E) return;
    int r = ei[e];
    int c = ei[E + e];
    int br = r >> 5, bc = c >> 5;
    if (br == bc && br < nb) {
        atomicMax(&win[br * (BSZ * BSZ) + (r & 31) * BSZ + (c & 31)], e);
    }
}

// ---------------- kernel 1b: winners write features + validity bit --------
__global__ void edge_feat_kernel(const int* __restrict__ ei,
                                 const float* __restrict__ ev,
                                 const float* __restrict__ pos,
                                 const int* __restrict__ win, int E,
                                 ushort_t* __restrict__ cellinfo,
                                 uint_t* __restrict__ vmap) {
    int e = blockIdx.x * blockDim.x + threadIdx.x;
    if (e >= E) return;
    int r = ei[e];
    int c = ei[E + e];
    int br = r >> 5, bc = c >> 5;
    if (br != bc) return;
    int rl = r & 31, cl = c & 31;
    int cell = br * 1024 + rl * 32 + cl;
    if (win[cell] != e) return;
    float d0 = pos[c * 3 + 0] - pos[r * 3 + 0];
    float d1 = pos[c * 3 + 1] - pos[r * 3 + 1];
    float d2 = pos[c * 3 + 2] - pos[r * 3 + 2];
    float d3 = ev[e];
    uint2 w; w.x = pk2(d0, d1); w.y = pk2(d2, d3);
    *(uint2*)&cellinfo[(size_t)cell * 4] = w;
    atomicOr(&vmap[br * 32 + rl], 1u << cl);
}

// ---------------- kernel 2: weights -> bf16 MFMA-fragment layout ----------
__global__ void wconv_kernel(const float* __restrict__ qkv_w,
                             const float* __restrict__ proj_w,
                             ushort_t* __restrict__ qkv_wf,
                             ushort_t* __restrict__ proj_wf) {
    int i = blockIdx.x * blockDim.x + threadIdx.x;   // (tile,ks,lane)
    int lane = i & 63, ks = (i >> 6) & 7, tile = i >> 9;
    int l15 = lane & 15, lg = lane >> 4;
    if (tile < 48) {
        const float* src = qkv_w + (size_t)(tile * 16 + l15) * 256 + ks * 32 + lg * 8;
        ushort_t* dst = qkv_wf + (size_t)i * 8;
        #pragma unroll
        for (int e = 0; e < 8; ++e) dst[e] = f2b(src[e]);
    }
    if (tile < 16) {
        const float* src = proj_w + (size_t)(tile * 16 + l15) * 256 + ks * 32 + lg * 8;
        ushort_t* dst = proj_wf + (size_t)i * 8;
        #pragma unroll
        for (int e = 0; e < 8; ++e) dst[e] = f2b(src[e]);
    }
}

// ---------------- fused kernel: qkv GEMM + attention + proj ---------------
// BM=64 (2 leaves), 512 threads, 1 WG/CU (128 KiB LDS), 2 waves/SIMD.
// qkv GEMM: x-fragments fully register-hoisted (xf[8][4]); tile-outer
// 2-set weight pipeline (one whole tile's 8 frags in flight while the
// previous tile's 32 MFMAs run).
//   [0      ,  32768) xb  bf16[64][256] swz8   -> comb overlay (16 KiB)
//   [32768  ,  65536) qs  chunk-frag [2][8192] -> xo overlay
//   [65536  ,  98304) ksm chunk-frag [2][8192]
//   [98304  , 131072) vs  vT [2][256ch][32row], XOR swz ((ch&3)<<3)
#define LS_XB   0
#define LS_QS   32768
#define LS_KS   65536
#define LS_VS   98304
#define LS_TOT  131072

__global__ __launch_bounds__(512, 2)
void fused_attn(const float* __restrict__ x,
                const ushort_t* __restrict__ qkv_wf,
                const float* __restrict__ qkv_b,
                const ushort_t* __restrict__ cellinfo,
                const uint_t* __restrict__ vmap,
                const ushort_t* __restrict__ proj_wf,
                const float* __restrict__ proj_b,
                const float* __restrict__ gate_w,
                const float* __restrict__ gate_b,
                float* __restrict__ out)
{
    __shared__ __align__(16) char smem[LS_TOT];
    ushort_t* xb   = (ushort_t*)(smem + LS_XB);
    ushort_t* comb = (ushort_t*)(smem + LS_XB);   // overlay (xb dead post-B2)
    ushort_t* qs   = (ushort_t*)(smem + LS_QS);
    ushort_t* xo   = (ushort_t*)(smem + LS_QS);   // overlay (qs dead post-B2b)
    ushort_t* ksm  = (ushort_t*)(smem + LS_KS);
    ushort_t* vs   = (ushort_t*)(smem + LS_VS);

    const int t = threadIdx.x;
    const int w = t >> 6, lane = t & 63, l15 = lane & 15, lg = lane >> 4;
    const int bi = blockIdx.x;
    const int mbase = bi * 64;

    // ---- P1: stage x -> bf16 LDS (swz8) ---------------------------------
    #pragma unroll
    for (int i = 0; i < 8; ++i) {
        int flat = i * 2048 + t * 4;
        int r = flat >> 8, c = flat & 255;
        float4 xv = *(const float4*)&x[(size_t)(mbase + r) * CH + c];
        uint2 wv; wv.x = pk2(xv.x, xv.y); wv.y = pk2(xv.z, xv.w);
        *(uint2*)&xb[r * 256 + (c ^ ((r & 7) << 3))] = wv;
    }
    __syncthreads();   // B1

    const int slB = (l15 & 7) << 3;
    const f32x4 zf = {0.f, 0.f, 0.f, 0.f};

    // ---- P2: qkv GEMM. xf register-hoisted; tile-outer weight pipeline --
    bf16x8 xf[8][4];
    #pragma unroll
    for (int ks = 0; ks < 8; ++ks) {
        int k0 = (ks * 32 + lg * 8) ^ slB;
        xf[ks][0] = *(const bf16x8*)&xb[l15 * 256 + k0];
        xf[ks][1] = *(const bf16x8*)&xb[(16 + l15) * 256 + k0];
        xf[ks][2] = *(const bf16x8*)&xb[(32 + l15) * 256 + k0];
        xf[ks][3] = *(const bf16x8*)&xb[(48 + l15) * 256 + k0];
    }

    bf16x8 wA[8], wB[8];

#define LOADT(dst, itv) { _Pragma("unroll")                                   \
        for (int ks_ = 0; ks_ < 8; ++ks_)                                     \
            dst[ks_] = *(const bf16x8*)(qkv_wf                                \
                + ((size_t)((((itv) * 8 + w) * 8) + ks_)) * 512 + lane * 8); }

#define TILE_COMPUTE(CUR, SW) { _Pragma("unroll")                             \
        for (int ks_ = 0; ks_ < 8; ++ks_) {                                   \
            if (SW) {                                                         \
                a0 = MFMA(CUR[ks_], xf[ks_][0], a0);                          \
                a1 = MFMA(CUR[ks_], xf[ks_][1], a1);                          \
                a2 = MFMA(CUR[ks_], xf[ks_][2], a2);                          \
                a3 = MFMA(CUR[ks_], xf[ks_][3], a3);                          \
            } else {                                                          \
                a0 = MFMA(xf[ks_][0], CUR[ks_], a0);                          \
                a1 = MFMA(xf[ks_][1], CUR[ks_], a1);                          \
                a2 = MFMA(xf[ks_][2], CUR[ks_], a2);                          \
                a3 = MFMA(xf[ks_][3], CUR[ks_], a3);                          \
            } } }

#define STORE_QK(ITV) {                                                       \
        int tt_ = (ITV) * 8 + w;                                              \
        f32x4 bv4_ = *(const f32x4*)&qkv_b[tt_ * 16 + lg * 4];                \
        ushort_t* dst_ = ((ITV) < 2) ? qs : ksm;                              \
        int tloc_ = ((ITV) < 2) ? tt_ : tt_ - 16;                             \
        f32x4 av_[4] = {a0, a1, a2, a3};                                      \
        _Pragma("unroll")                                                     \
        for (int m_ = 0; m_ < 4; ++m_) {                                      \
            f32x4 v_ = av_[m_] + bv4_;                                        \
            uint2 wv_; wv_.x = pk2(v_[0], v_[1]); wv_.y = pk2(v_[2], v_[3]);  \
            *(uint2*)&dst_[(m_ >> 1) * 8192 + (tloc_ * 2 + (m_ & 1)) * 256    \
                           + lane * 4] = wv_;                                 \
        } }

#define STORE_V(ITV) {                                                        \
        int tt_ = (ITV) * 8 + w;                                              \
        int vch_ = (tt_ - 32) * 16 + l15;                                     \
        float bv_ = qkv_b[512 + vch_];                                        \
        int swzv_ = (vch_ & 3) << 3;                                          \
        f32x4 av_[4] = {a0, a1, a2, a3};                                      \
        _Pragma("unroll")                                                     \
        for (int m_ = 0; m_ < 4; ++m_) {                                      \
            f32x4 v_ = av_[m_];                                               \
            uint2 wv_; wv_.x = pk2(v_[0] + bv_, v_[1] + bv_);                 \
            wv_.y = pk2(v_[2] + bv_, v_[3] + bv_);                            \
            int roff_ = (((m_ & 1) * 16 + lg * 4)) ^ swzv_;                   \
            *(uint2*)&vs[(m_ >> 1) * 8192 + vch_ * 32 + roff_] = wv_;         \
        } }

#define DO_TILE(ITV, CUR) {                                                   \
        f32x4 a0 = zf, a1 = zf, a2 = zf, a3 = zf;                             \
        if ((ITV) < 4) { TILE_COMPUTE(CUR, 1) STORE_QK(ITV) }                 \
        else           { TILE_COMPUTE(CUR, 0) STORE_V(ITV) } }

    LOADT(wA, 0); LOADT(wB, 1);
    DO_TILE(0, wA); LOADT(wA, 2);
    DO_TILE(1, wB); LOADT(wB, 3);
    DO_TILE(2, wA); LOADT(wA, 4);
    DO_TILE(3, wB); LOADT(wB, 5);
    DO_TILE(4, wA);
    DO_TILE(5, wB);

    // ---- cellinfo + validity preload (global; hides under barrier) ------
    const int gl = w >> 2, h = w & 3;
    const ushort_t* crow = cellinfo + (size_t)(bi * 2 + gl) * 4096;
    uint4 cellA[2][2], cellB[2][2];
    uint_t vmq[2];
    #pragma unroll
    for (int qt = 0; qt < 2; ++qt) {
        int qi = qt * 16 + l15;
        vmq[qt] = vmap[(size_t)(bi * 2 + gl) * 32 + qi];
        #pragma unroll
        for (int kt = 0; kt < 2; ++kt) {
            int kj0 = kt * 16 + lg * 4;
            const uint_t* cp = (const uint_t*)(crow + ((size_t)qi * 32 + kj0) * 4);
            cellA[qt][kt] = *(const uint4*)cp;
            cellB[qt][kt] = *(const uint4*)(cp + 4);
        }
    }
    const float gw0 = gate_w[h * 4 + 0], gw1 = gate_w[h * 4 + 1];
    const float gw2 = gate_w[h * 4 + 2], gw3 = gate_w[h * 4 + 3];
    const float gb  = gate_b[h];

    __syncthreads();   // B2: qkv LDS stores visible; xb dead from here

    // ---- P3: fragment loads (LDS) ---------------------------------------
    uint4 qld[2][2], kld[2][2];
    #pragma unroll
    for (int rt = 0; rt < 2; ++rt) {
        #pragma unroll
        for (int ks2 = 0; ks2 < 2; ++ks2) {
            int ttq = h * 4 + ks2 * 2 + (lg >> 1);
            int a0 = gl * 8192 + (ttq * 2 + rt) * 256 + ((lg & 1) * 32 + l15) * 4;
            uint2 u0 = *(const uint2*)&qs[a0];
            uint2 u1 = *(const uint2*)&qs[a0 + 64];
            qld[rt][ks2] = (uint4){u0.x, u0.y, u1.x, u1.y};
            uint2 w0 = *(const uint2*)&ksm[a0];
            uint2 w1 = *(const uint2*)&ksm[a0 + 64];
            kld[rt][ks2] = (uint4){w0.x, w0.y, w1.x, w1.y};
        }
    }
    bf16x8 vf[4];
    #pragma unroll
    for (int ct = 0; ct < 4; ++ct) {
        int off = (lg * 8) ^ ((l15 & 3) << 3);
        vf[ct] = *(const bf16x8*)&vs[gl * 8192
                                     + (h * 64 + ct * 16 + l15) * 32 + off];
    }
    __syncthreads();   // B2b: all qs/ksm reads done -> xo overlay safe

    // ---- P4: scores MFMA (A=k M=kj, B=q N=qi) ---------------------------
    f32x4 s[2][2];
    #pragma unroll
    for (int qt = 0; qt < 2; ++qt) { s[qt][0] = zf; s[qt][1] = zf; }
    #pragma unroll
    for (int qt = 0; qt < 2; ++qt) {
        #pragma unroll
        for (int ks2 = 0; ks2 < 2; ++ks2) {
            bf16x8 qf = __builtin_bit_cast(bf16x8, qld[qt][ks2]);
            #pragma unroll
            for (int kt = 0; kt < 2; ++kt)
                s[qt][kt] = MFMA(__builtin_bit_cast(bf16x8, kld[kt][ks2]),
                                 qf, s[qt][kt]);
        }
    }

    // ---- P5: softmax + gate; validity from bitmap -----------------------
    #pragma unroll
    for (int qt = 0; qt < 2; ++qt) {
        int qi = qt * 16 + l15;
        float r[8], gt[8];
        float rawsum = 0.f;
        #pragma unroll
        for (int kt = 0; kt < 2; ++kt) {
            int kj0 = kt * 16 + lg * 4;
            uint4 cA = cellA[qt][kt], cB = cellB[qt][kt];
            uint_t d01[4] = {cA.x, cA.z, cB.x, cB.z};
            uint_t d23[4] = {cA.y, cA.w, cB.y, cB.w};
            #pragma unroll
            for (int j = 0; j < 4; ++j) {
                int kj = kj0 + j;
                bool fixed = (kj == qi);
                bool validb = (vmq[qt] >> kj) & 1u;
                float e3 = b2f((ushort_t)(d23[j] >> 16));
                float sb = fixed ? 1.0f : (validb ? e3 : -INFINITY);
                float g;
                if (fixed)       g = gw3 + gb;
                else if (validb) g = b2f((ushort_t)(d01[j] & 0xFFFF)) * gw0
                                   + b2f((ushort_t)(d01[j] >> 16))    * gw1
                                   + b2f((ushort_t)(d23[j] & 0xFFFF)) * gw2
                                   + e3 * gw3 + gb;
                else             g = 0.0f;
                float sraw = s[qt][kt][j];
                rawsum += sraw;
                r[kt * 4 + j]  = sraw * 0.125f + sb;
                gt[kt * 4 + j] = g;
            }
        }
        rawsum += __shfl_xor(rawsum, 16);
        rawsum += __shfl_xor(rawsum, 32);
        float r2 = rawsum * (0.125f / 32.0f) + 1.0f;

        float m = fmaxf(fmaxf(fmaxf(r[0], r[1]), fmaxf(r[2], r[3])),
                        fmaxf(fmaxf(r[4], r[5]), fmaxf(r[6], r[7])));
        m = fmaxf(m, r2);
        m = fmaxf(m, __shfl_xor(m, 16));
        m = fmaxf(m, __shfl_xor(m, 32));
        float sum = 0.f;
        #pragma unroll
        for (int i = 0; i < 8; ++i) { r[i] = __expf(r[i] - m); sum += r[i]; }
        sum += __shfl_xor(sum, 16);
        sum += __shfl_xor(sum, 32);
        float e2 = __expf(r2 - m);
        float inv = 1.0f / (sum + e2);
        float comb32 = e2 * inv + (gw3 + gb);
        float cadd = comb32 * 0.03125f;     // fold kj=32 PV into every entry
        int swz = (l15 & 3) << 3;
        #pragma unroll
        for (int kt = 0; kt < 2; ++kt) {
            int kj0 = kt * 16 + lg * 4;
            uint2 wv;
            wv.x = pk2(r[kt*4+0] * inv + gt[kt*4+0] + cadd,
                       r[kt*4+1] * inv + gt[kt*4+1] + cadd);
            wv.y = pk2(r[kt*4+2] * inv + gt[kt*4+2] + cadd,
                       r[kt*4+3] * inv + gt[kt*4+3] + cadd);
            *(uint2*)&comb[(gl * 4 + h) * 1024 + qi * 32 + (kj0 ^ swz)] = wv;
        }
    }
    // comb is wave-private -> no barrier

    // ---- P6: PV MFMA (A=vT M=c, B=comb N=qi) -> xo ----------------------
    bf16x8 cfr[2];
    #pragma unroll
    for (int qt = 0; qt < 2; ++qt) {
        int qi = qt * 16 + l15;
        int off = (lg * 8) ^ ((l15 & 3) << 3);
        cfr[qt] = *(const bf16x8*)&comb[(gl * 4 + h) * 1024 + qi * 32 + off];
    }
    #pragma unroll
    for (int ct = 0; ct < 4; ++ct) {
        #pragma unroll
        for (int qt = 0; qt < 2; ++qt) {
            f32x4 acc2 = zf;
            acc2 = MFMA(vf[ct], cfr[qt], acc2);
            int qi = qt * 16 + l15;
            uint2 wv;
            wv.x = pk2(acc2[0], acc2[1]);
            wv.y = pk2(acc2[2], acc2[3]);
            int c0 = h * 64 + ct * 16 + lg * 4;
            *(uint2*)&xo[gl * 8192 + qi * 256 + (c0 ^ ((l15 & 7) << 3))] = wv;
        }
    }
    __syncthreads();   // B3: xo read cross-wave by proj

    // ---- P7: proj, 2 out-ch tiles per wave, 2-deep weight pipeline ------
    {
        const int slR = (l15 & 7) << 3;
        bf16x8 pw[2][8];
        #pragma unroll
        for (int i = 0; i < 2; ++i) {
            int pt = w * 2 + i;
            #pragma unroll
            for (int ks = 0; ks < 8; ++ks)
                pw[i][ks] = *(const bf16x8*)(proj_wf
                               + ((size_t)(pt * 8 + ks)) * 512 + lane * 8);
        }
        f32x4 pacc[2][4];
        #pragma unroll
        for (int i = 0; i < 2; ++i)
            #pragma unroll
            for (int rt = 0; rt < 4; ++rt) pacc[i][rt] = zf;
        #pragma unroll
        for (int ks = 0; ks < 8; ++ks) {
            int k0 = ks * 32 + lg * 8;
            #pragma unroll
            for (int rt = 0; rt < 4; ++rt) {
                bf16x8 bfr = *(const bf16x8*)&xo[(rt >> 1) * 8192
                                 + ((rt & 1) * 16 + l15) * 256 + (k0 ^ slR)];
                pacc[0][rt] = MFMA(pw[0][ks], bfr, pacc[0][rt]);
                pacc[1][rt] = MFMA(pw[1][ks], bfr, pacc[1][rt]);
            }
        }
        #pragma unroll
        for (int i = 0; i < 2; ++i) {
            int pt = w * 2 + i, n0 = pt * 16;
            f32x4 bv = *(const f32x4*)&proj_b[n0 + lg * 4];
            #pragma unroll
            for (int rt = 0; rt < 4; ++rt) {
                f32x4 o = pacc[i][rt] + bv;
                int row = mbase + (rt >> 1) * 32 + (rt & 1) * 16 + l15;
                *(f32x4*)&out[(size_t)row * 256 + n0 + lg * 4] = o;
            }
        }
    }
}

extern "C" void kernel_launch(void* const* d_in, const int* in_sizes, int n_in,
                              void* d_out, int out_size, void* d_ws, size_t ws_size,
                              hipStream_t stream) {
    const float* x      = (const float*)d_in[0];
    const int*   ei     = (const int*)  d_in[1];
    const float* ev     = (const float*)d_in[2];
    const float* pos    = (const float*)d_in[3];
    const float* qkv_w  = (const float*)d_in[4];
    const float* qkv_b  = (const float*)d_in[5];
    const float* proj_w = (const float*)d_in[6];
    const float* proj_b = (const float*)d_in[7];
    const float* gate_w = (const float*)d_in[8];
    const float* gate_b = (const float*)d_in[9];
    float* out = (float*)d_out;

    const int E  = in_sizes[2];
    const int N  = in_sizes[0] / CH;
    const int nb = N / BSZ;

    char* ws = (char*)d_ws;
    int*      win      = (int*)ws;                               // nb*4096 B
    uint_t*   vmap     = (uint_t*)(ws + (size_t)nb * 4096);      // nb*128 B
    ushort_t* cellinfo = (ushort_t*)(ws + (size_t)nb * 4224);    // nb*8192 B
    size_t off = (size_t)nb * 12416;
    ushort_t* qkv_wf  = (ushort_t*)(ws + off); off += 48 * 8 * 64 * 8 * 2;
    ushort_t* proj_wf = (ushort_t*)(ws + off); off += 16 * 8 * 64 * 8 * 2;

    hipMemsetAsync(win, 0xFF, (size_t)nb * 4096, stream);   // win = -1
    hipMemsetAsync(vmap, 0x00, (size_t)nb * 128, stream);   // validity = 0
    edge_win_kernel<<<(E + 255) / 256, 256, 0, stream>>>(ei, E, nb, win);
    edge_feat_kernel<<<(E + 255) / 256, 256, 0, stream>>>(ei, ev, pos, win, E,
                                                          cellinfo, vmap);
    wconv_kernel<<<96, 256, 0, stream>>>(qkv_w, proj_w, qkv_wf, proj_wf);
    fused_attn<<<nb / 2, 512, 0, stream>>>(x, qkv_wf, qkv_b, cellinfo, vmap,
                                           proj_wf, proj_b, gate_w, gate_b, out);
}

// Round 12
// 238.765 us; speedup vs baseline: 1.1583x; 1.1292x over previous
//
#include <hip/hip_runtime.h>
#include <math.h>

#define BSZ 32
#define CH  256

typedef short  bf16x8 __attribute__((ext_vector_type(8)));
typedef float  f32x4  __attribute__((ext_vector_type(4)));
typedef unsigned short ushort_t;
typedef unsigned int   uint_t;

#define MFMA(a, b, c) __builtin_amdgcn_mfma_f32_16x16x32_bf16((a), (b), (c), 0, 0, 0)

__device__ __forceinline__ ushort_t f2b(float f) {
    uint_t u = __builtin_bit_cast(uint_t, f);
    uint_t r = (u + 0x7FFFu + ((u >> 16) & 1u)) >> 16;   // RTNE
    return (ushort_t)r;
}
__device__ __forceinline__ float b2f(ushort_t u) {
    uint_t v = ((uint_t)u) << 16;
    return __builtin_bit_cast(float, v);
}
__device__ __forceinline__ uint_t pk2(float a, float b) {
    return (uint_t)f2b(a) | ((uint_t)f2b(b) << 16);
}

// ---------------- kernel 1: per-cell winning edge (last write wins) -------
__global__ void edge_win_kernel(const int* __restrict__ ei, int E, int nb,
                                int* __restrict__ win) {
    int e = blockIdx.x * blockDim.x + threadIdx.x;
    if (e >= E) return;
    int r = ei[e];
    int c = ei[E + e];
    int br = r >> 5, bc = c >> 5;
    if (br == bc && br < nb) {
        atomicMax(&win[br * (BSZ * BSZ) + (r & 31) * BSZ + (c & 31)], e);
    }
}

// ---------------- kernel 1b: per-node gate projection ---------------------
// pg[h*N + n] = dot(pos[n], gate_w[h][0:3]) — the pos-part of the gate is
// linear per node, so dx*gw0+dy*gw1+dz*gw2 == pg[c] - pg[r].
__global__ void pgate_kernel(const float* __restrict__ pos,
                             const float* __restrict__ gate_w,
                             float* __restrict__ pg, int N) {
    int n = blockIdx.x * 256 + threadIdx.x;
    int h = blockIdx.y;
    if (n >= N) return;
    pg[(size_t)h * N + n] = pos[n * 3 + 0] * gate_w[h * 4 + 0]
                          + pos[n * 3 + 1] * gate_w[h * 4 + 1]
                          + pos[n * 3 + 2] * gate_w[h * 4 + 2];
}

// ---------------- kernel 2: weights -> bf16 MFMA-fragment layout ----------
__global__ void wconv_kernel(const float* __restrict__ qkv_w,
                             const float* __restrict__ proj_w,
                             ushort_t* __restrict__ qkv_wf,
                             ushort_t* __restrict__ proj_wf) {
    int i = blockIdx.x * blockDim.x + threadIdx.x;   // (tile,ks,lane)
    int lane = i & 63, ks = (i >> 6) & 7, tile = i >> 9;
    int l15 = lane & 15, lg = lane >> 4;
    if (tile < 48) {
        const float* src = qkv_w + (size_t)(tile * 16 + l15) * 256 + ks * 32 + lg * 8;
        ushort_t* dst = qkv_wf + (size_t)i * 8;
        #pragma unroll
        for (int e = 0; e < 8; ++e) dst[e] = f2b(src[e]);
    }
    if (tile < 16) {
        const float* src = proj_w + (size_t)(tile * 16 + l15) * 256 + ks * 32 + lg * 8;
        ushort_t* dst = proj_wf + (size_t)i * 8;
        #pragma unroll
        for (int e = 0; e < 8; ++e) dst[e] = f2b(src[e]);
    }
}

// ---------------- fused kernel: BM=64, wave = head, in-wave everything ----
// 256 threads (4 waves). Wave h computes q,k,v for ch [h*64,(h+1)*64) of
// BOTH leaves (weights loaded once per WG -> BM=64 traffic), converts
// D-frags to attention frags via the wave-private scr repack (R10-proven),
// runs scores/softmax/PV in registers. No q/k/v LDS. 3 barriers.
// LDS: xb 32K (-> xo overlay post-B2) + scr 4x1216 = 37632 B.
#define LS_SCR 32768
#define LS_TOT 37632

__global__ __launch_bounds__(256, 2)
void fused_attn(const float* __restrict__ x,
                const ushort_t* __restrict__ qkv_wf,
                const float* __restrict__ qkv_b,
                const int* __restrict__ win,
                const float* __restrict__ ev,
                const float* __restrict__ pg,
                const ushort_t* __restrict__ proj_wf,
                const float* __restrict__ proj_b,
                const float* __restrict__ gate_w,
                const float* __restrict__ gate_b,
                float* __restrict__ out, int N)
{
    __shared__ __align__(16) char smem[LS_TOT];
    ushort_t* xb = (ushort_t*)(smem);
    ushort_t* xo = (ushort_t*)(smem);      // overlay: xb dead post-B2

    const int t = threadIdx.x;
    const int h = t >> 6, lane = t & 63, l15 = lane & 15, lg = lane >> 4;
    const int bi = blockIdx.x, mbase = bi * 64;
    ushort_t* scr = (ushort_t*)(smem + LS_SCR + h * 1216);

    // ---- P1: stage x -> bf16 LDS (swz8) ---------------------------------
    #pragma unroll
    for (int i = 0; i < 16; ++i) {
        int flat = i * 1024 + t * 4;
        int r = flat >> 8, c = flat & 255;
        float4 xv = *(const float4*)&x[(size_t)(mbase + r) * CH + c];
        uint2 wv; wv.x = pk2(xv.x, xv.y); wv.y = pk2(xv.z, xv.w);
        *(uint2*)&xb[r * 256 + (c ^ ((r & 7) << 3))] = wv;
    }
    __syncthreads();   // B1

    const int slB = (l15 & 7) << 3;
    const f32x4 zf = {0.f, 0.f, 0.f, 0.f};

    // wave-private 16x32 repack (R10-proven): D-frag pair -> A/B-frag.
    auto repack16 = [&](f32x4 a0, f32x4 a1) -> bf16x8 {
        uint2 w0, w1;
        w0.x = pk2(a0[0], a0[1]); w0.y = pk2(a0[2], a0[3]);
        w1.x = pk2(a1[0], a1[1]); w1.y = pk2(a1[2], a1[3]);
        *(uint2*)&scr[l15 * 38 + lg * 4]      = w0;
        *(uint2*)&scr[l15 * 38 + 16 + lg * 4] = w1;
        return *(const bf16x8*)&scr[l15 * 38 + lg * 8];
    };

    bf16x8 qld[2][2][2], kld[2][2][2], vf[2][4];

#define QK_SECTION(TB, DST)                                                   \
    _Pragma("unroll")                                                         \
    for (int p = 0; p < 2; ++p) {                                             \
        const int T0 = (TB) + p * 2, T1 = T0 + 1;                             \
        bf16x8 W0[8], W1[8];                                                  \
        _Pragma("unroll")                                                     \
        for (int ks = 0; ks < 8; ++ks) {                                      \
            W0[ks] = *(const bf16x8*)(qkv_wf                                  \
                        + ((size_t)(T0 * 8 + ks)) * 512 + lane * 8);          \
            W1[ks] = *(const bf16x8*)(qkv_wf                                  \
                        + ((size_t)(T1 * 8 + ks)) * 512 + lane * 8);          \
        }                                                                     \
        f32x4 a0[4], a1[4];                                                   \
        _Pragma("unroll")                                                     \
        for (int m = 0; m < 4; ++m) { a0[m] = zf; a1[m] = zf; }               \
        __builtin_amdgcn_s_setprio(1);                                        \
        _Pragma("unroll")                                                     \
        for (int ks = 0; ks < 8; ++ks) {                                      \
            int k0 = (ks * 32 + lg * 8) ^ slB;                                \
            _Pragma("unroll")                                                 \
            for (int m = 0; m < 4; ++m) {                                     \
                bf16x8 xf = *(const bf16x8*)&xb[(m * 16 + l15) * 256 + k0];   \
                a0[m] = MFMA(W0[ks], xf, a0[m]);                              \
                a1[m] = MFMA(W1[ks], xf, a1[m]);                              \
            }                                                                 \
        }                                                                     \
        __builtin_amdgcn_s_setprio(0);                                        \
        f32x4 b0v = *(const f32x4*)&qkv_b[T0 * 16 + lg * 4];                  \
        f32x4 b1v = *(const f32x4*)&qkv_b[T1 * 16 + lg * 4];                  \
        _Pragma("unroll")                                                     \
        for (int m = 0; m < 4; ++m) { a0[m] += b0v; a1[m] += b1v; }           \
        _Pragma("unroll")                                                     \
        for (int gl = 0; gl < 2; ++gl)                                        \
            _Pragma("unroll")                                                 \
            for (int rt = 0; rt < 2; ++rt)                                    \
                DST[gl][rt][p] = repack16(a0[gl * 2 + rt], a1[gl * 2 + rt]);  \
    }

    // ---- P2: q section (swapped: D[ch][row]) -> qld B-frags -------------
    QK_SECTION(h * 4, qld)
    // ---- P3: k section -> kld A-frags -----------------------------------
    QK_SECTION(16 + h * 4, kld)

    // ---- preload win / pgate (overlaps v section + B2) ------------------
    uint4  wv4[2][2][2];
    float4 pgc[2][2];
    float  pgr[2][2];
    #pragma unroll
    for (int gl = 0; gl < 2; ++gl) {
        int cb = mbase + gl * 32;
        #pragma unroll
        for (int qt = 0; qt < 2; ++qt) {
            int qi = qt * 16 + l15;
            wv4[gl][qt][0] = *(const uint4*)&win[(size_t)(bi * 2 + gl) * 1024
                                                + qi * 32 + lg * 4];
            wv4[gl][qt][1] = *(const uint4*)&win[(size_t)(bi * 2 + gl) * 1024
                                                + qi * 32 + 16 + lg * 4];
            pgr[gl][qt] = pg[(size_t)h * N + cb + qi];
        }
        pgc[gl][0] = *(const float4*)&pg[(size_t)h * N + cb + lg * 4];
        pgc[gl][1] = *(const float4*)&pg[(size_t)h * N + cb + 16 + lg * 4];
    }

    // ---- P4: v section (non-swapped: D[row][ch]) -> vf A-frags ----------
    #pragma unroll
    for (int ct = 0; ct < 4; ++ct) {
        int T = 32 + h * 4 + ct;
        bf16x8 W[8];
        #pragma unroll
        for (int ks = 0; ks < 8; ++ks)
            W[ks] = *(const bf16x8*)(qkv_wf + ((size_t)(T * 8 + ks)) * 512 + lane * 8);
        f32x4 a[4];
        #pragma unroll
        for (int m = 0; m < 4; ++m) a[m] = zf;
        __builtin_amdgcn_s_setprio(1);
        #pragma unroll
        for (int ks = 0; ks < 8; ++ks) {
            int k0 = (ks * 32 + lg * 8) ^ slB;
            #pragma unroll
            for (int m = 0; m < 4; ++m) {
                bf16x8 xf = *(const bf16x8*)&xb[(m * 16 + l15) * 256 + k0];
                a[m] = MFMA(xf, W[ks], a[m]);
            }
        }
        __builtin_amdgcn_s_setprio(0);
        float bvs = qkv_b[T * 16 + l15];
        f32x4 bb = {bvs, bvs, bvs, bvs};
        #pragma unroll
        for (int m = 0; m < 4; ++m) a[m] += bb;
        vf[0][ct] = repack16(a[0], a[1]);
        vf[1][ct] = repack16(a[2], a[3]);
    }
    __syncthreads();   // B2: all waves' xb reads done -> xo overlay safe

    const float gw3v = gate_w[h * 4 + 3];
    const float gbv  = gate_b[h];
    const float g3b  = gw3v + gbv;

    // ---- P5: per-leaf attention (all in-wave) ---------------------------
    #pragma unroll
    for (int gl = 0; gl < 2; ++gl) {
        // ev gathers (issued first; overlap scores)
        float evv[2][8];
        #pragma unroll
        for (int qt = 0; qt < 2; ++qt)
            #pragma unroll
            for (int kt = 0; kt < 2; ++kt) {
                const int* wp = (const int*)&wv4[gl][qt][kt];
                #pragma unroll
                for (int j = 0; j < 4; ++j) {
                    int e = wp[j];
                    evv[qt][kt * 4 + j] = ev[e < 0 ? 0 : e];
                }
            }

        // scores MFMA (A=k M=kj, B=q N=qi)
        f32x4 s[2][2];
        #pragma unroll
        for (int qt = 0; qt < 2; ++qt) { s[qt][0] = zf; s[qt][1] = zf; }
        __builtin_amdgcn_s_setprio(1);
        #pragma unroll
        for (int qt = 0; qt < 2; ++qt)
            #pragma unroll
            for (int p = 0; p < 2; ++p)
                #pragma unroll
                for (int kt = 0; kt < 2; ++kt)
                    s[qt][kt] = MFMA(kld[gl][kt][p], qld[gl][qt][p], s[qt][kt]);
        __builtin_amdgcn_s_setprio(0);

        // softmax + gate; kj=32 via mean of raw scores (linearity)
        bf16x8 cfr[2];
        #pragma unroll
        for (int qt = 0; qt < 2; ++qt) {
            int qi = qt * 16 + l15;
            float r[8], gt[8];
            float rawsum = 0.f;
            #pragma unroll
            for (int kt = 0; kt < 2; ++kt) {
                const int* wp = (const int*)&wv4[gl][qt][kt];
                #pragma unroll
                for (int j = 0; j < 4; ++j) {
                    int kj = kt * 16 + lg * 4 + j;
                    bool fixed = (kj == qi);
                    bool valid = wp[j] >= 0;
                    float e3 = evv[qt][kt * 4 + j];
                    float sb = fixed ? 1.0f : (valid ? e3 : -INFINITY);
                    float pgcv = ((const float*)&pgc[gl][kt])[j];
                    float g = fixed ? g3b
                            : (valid ? (pgcv - pgr[gl][qt] + e3 * gw3v + gbv) : 0.0f);
                    float sraw = s[qt][kt][j];
                    rawsum += sraw;
                    r[kt * 4 + j]  = sraw * 0.125f + sb;
                    gt[kt * 4 + j] = g;
                }
            }
            rawsum += __shfl_xor(rawsum, 16);
            rawsum += __shfl_xor(rawsum, 32);
            float r2 = rawsum * (0.125f / 32.0f) + 1.0f;

            float m = fmaxf(fmaxf(fmaxf(r[0], r[1]), fmaxf(r[2], r[3])),
                            fmaxf(fmaxf(r[4], r[5]), fmaxf(r[6], r[7])));
            m = fmaxf(m, r2);
            m = fmaxf(m, __shfl_xor(m, 16));
            m = fmaxf(m, __shfl_xor(m, 32));
            float sum = 0.f;
            #pragma unroll
            for (int i = 0; i < 8; ++i) { r[i] = __expf(r[i] - m); sum += r[i]; }
            sum += __shfl_xor(sum, 16);
            sum += __shfl_xor(sum, 32);
            float e2 = __expf(r2 - m);
            float inv = 1.0f / (sum + e2);
            float comb32 = e2 * inv + g3b;
            float cadd = comb32 * 0.03125f;   // fold kj=32 PV into every entry
            f32x4 ra = {r[0] * inv + gt[0] + cadd, r[1] * inv + gt[1] + cadd,
                        r[2] * inv + gt[2] + cadd, r[3] * inv + gt[3] + cadd};
            f32x4 rb = {r[4] * inv + gt[4] + cadd, r[5] * inv + gt[5] + cadd,
                        r[6] * inv + gt[6] + cadd, r[7] * inv + gt[7] + cadd};
            cfr[qt] = repack16(ra, rb);       // B-frag: l15=qi, lg*8+e=kj
        }

        // PV MFMA (A=v M=ch, B=comb N=qi) -> xo (xb overlay)
        __builtin_amdgcn_s_setprio(1);
        #pragma unroll
        for (int ct = 0; ct < 4; ++ct) {
            #pragma unroll
            for (int qt = 0; qt < 2; ++qt) {
                f32x4 a2 = zf;
                a2 = MFMA(vf[gl][ct], cfr[qt], a2);
                int qi = qt * 16 + l15;
                uint2 wv;
                wv.x = pk2(a2[0], a2[1]);
                wv.y = pk2(a2[2], a2[3]);
                int c0 = h * 64 + ct * 16 + lg * 4;
                *(uint2*)&xo[gl * 8192 + qi * 256 + (c0 ^ ((l15 & 7) << 3))] = wv;
            }
        }
        __builtin_amdgcn_s_setprio(0);
    }
    __syncthreads();   // B3: xo read cross-wave by proj

    // ---- P6: proj (wave h: tiles h*4+i), 2-deep weight pipeline ---------
    {
        const int slR = (l15 & 7) << 3;
        bf16x8 pwA[4], pwB[4];
        f32x4 pacc[4][4];
        #pragma unroll
        for (int i = 0; i < 4; ++i)
            #pragma unroll
            for (int rt = 0; rt < 4; ++rt) pacc[i][rt] = zf;

#define LOADPW(dst, kss) { _Pragma("unroll")                                  \
        for (int i_ = 0; i_ < 4; ++i_)                                        \
            dst[i_] = *(const bf16x8*)(proj_wf                                \
                + ((size_t)((h * 4 + i_) * 8 + (kss))) * 512 + lane * 8); }

#define PCOMP(pw, kss) { int k0_ = (kss) * 32 + lg * 8;                       \
        _Pragma("unroll")                                                     \
        for (int rt_ = 0; rt_ < 4; ++rt_) {                                   \
            bf16x8 b_ = *(const bf16x8*)&xo[(rt_ >> 1) * 8192                 \
                         + ((rt_ & 1) * 16 + l15) * 256 + (k0_ ^ slR)];       \
            _Pragma("unroll")                                                 \
            for (int i_ = 0; i_ < 4; ++i_)                                    \
                pacc[i_][rt_] = MFMA(pw[i_], b_, pacc[i_][rt_]);              \
        } }

        LOADPW(pwA, 0); LOADPW(pwB, 1);
        __builtin_amdgcn_s_setprio(1);
        PCOMP(pwA, 0);  LOADPW(pwA, 2);
        PCOMP(pwB, 1);  LOADPW(pwB, 3);
        PCOMP(pwA, 2);  LOADPW(pwA, 4);
        PCOMP(pwB, 3);  LOADPW(pwB, 5);
        PCOMP(pwA, 4);  LOADPW(pwA, 6);
        PCOMP(pwB, 5);  LOADPW(pwB, 7);
        PCOMP(pwA, 6);
        PCOMP(pwB, 7);
        __builtin_amdgcn_s_setprio(0);

        #pragma unroll
        for (int i = 0; i < 4; ++i) {
            int n0 = (h * 4 + i) * 16;
            f32x4 bv = *(const f32x4*)&proj_b[n0 + lg * 4];
            #pragma unroll
            for (int rt = 0; rt < 4; ++rt) {
                f32x4 o = pacc[i][rt] + bv;
                int row = mbase + (rt >> 1) * 32 + (rt & 1) * 16 + l15;
                *(f32x4*)&out[(size_t)row * 256 + n0 + lg * 4] = o;
            }
        }
    }
}

extern "C" void kernel_launch(void* const* d_in, const int* in_sizes, int n_in,
                              void* d_out, int out_size, void* d_ws, size_t ws_size,
                              hipStream_t stream) {
    const float* x      = (const float*)d_in[0];
    const int*   ei     = (const int*)  d_in[1];
    const float* ev     = (const float*)d_in[2];
    const float* pos    = (const float*)d_in[3];
    const float* qkv_w  = (const float*)d_in[4];
    const float* qkv_b  = (const float*)d_in[5];
    const float* proj_w = (const float*)d_in[6];
    const float* proj_b = (const float*)d_in[7];
    const float* gate_w = (const float*)d_in[8];
    const float* gate_b = (const float*)d_in[9];
    float* out = (float*)d_out;

    const int E  = in_sizes[2];
    const int N  = in_sizes[0] / CH;
    const int nb = N / BSZ;

    char* ws = (char*)d_ws;
    int*   win = (int*)ws;                                   // nb*4096 B
    float* pg  = (float*)(ws + (size_t)nb * 4096);           // 4*N*4 B
    size_t off = (size_t)nb * 4096 + (size_t)4 * N * 4;
    ushort_t* qkv_wf  = (ushort_t*)(ws + off); off += 48 * 8 * 64 * 8 * 2;
    ushort_t* proj_wf = (ushort_t*)(ws + off); off += 16 * 8 * 64 * 8 * 2;

    hipMemsetAsync(win, 0xFF, (size_t)nb * 4096, stream);    // win = -1
    edge_win_kernel<<<(E + 255) / 256, 256, 0, stream>>>(ei, E, nb, win);
    pgate_kernel<<<dim3((N + 255) / 256, 4), 256, 0, stream>>>(pos, gate_w, pg, N);
    wconv_kernel<<<96, 256, 0, stream>>>(qkv_w, proj_w, qkv_wf, proj_wf);
    fused_attn<<<nb / 2, 256, 0, stream>>>(x, qkv_wf, qkv_b, win, ev, pg,
                                           proj_wf, proj_b, gate_w, gate_b,
                                           out, N);
}